// Round 4
// baseline (105.890 us; speedup 1.0000x reference)
//
#include <hip/hip_runtime.h>
#include <cstdint>

#define B_ 16
#define S_ 1024
#define D_ 512
#define TILE 128
#define BK 32
#define PITCH 36   // legacy-path LDS pitch

typedef float f32x4 __attribute__((ext_vector_type(4)));
typedef short s16x8 __attribute__((ext_vector_type(8)));
typedef unsigned short u16;
typedef unsigned int u32;

__device__ __forceinline__ u16 f2bf(float f) {
    u32 u = __builtin_bit_cast(u32, f);
    u += 0x7FFFu + ((u >> 16) & 1u);
    return (u16)(u >> 16);
}

#define GLD16(g, l) __builtin_amdgcn_global_load_lds( \
    (const __attribute__((address_space(1))) u32*)(g), \
    (__attribute__((address_space(3))) u32*)(l), 16, 0, 0)

// fp32 -> bf16 elementwise (used for K only now)
__global__ __launch_bounds__(256) void cvt_kernel(const float* __restrict__ src,
                                                  u16* __restrict__ dst) {
    int i = (blockIdx.x * 256 + threadIdx.x) * 8;
    float4 a = *(const float4*)(src + i);
    float4 b = *(const float4*)(src + i + 4);
    union { ushort4 h[2]; s16x8 v; } r;
    r.h[0] = make_ushort4(f2bf(a.x), f2bf(a.y), f2bf(a.z), f2bf(a.w));
    r.h[1] = make_ushort4(f2bf(b.x), f2bf(b.y), f2bf(b.z), f2bf(b.w));
    *(s16x8*)(dst + i) = r.v;
}

// V [B,S,D] fp32 -> V^T [B,D,S] bf16
#define TP 66
__global__ __launch_bounds__(256) void trv_kernel(const float* __restrict__ v,
                                                  u16* __restrict__ vt) {
    const int d0 = blockIdx.x * 64, j0 = blockIdx.y * 64, b = blockIdx.z;
    __shared__ u16 t[64 * TP];
    const int tid = threadIdx.x;
    const int tj = tid >> 2;
    const int td = (tid & 3) * 16;
    const float* src = v + ((size_t)b * S_ + j0 + tj) * D_ + d0 + td;
#pragma unroll
    for (int e = 0; e < 4; ++e) {
        float4 a = *(const float4*)(src + e * 4);
        *(ushort4*)(t + tj * TP + td + e * 4) =
            make_ushort4(f2bf(a.x), f2bf(a.y), f2bf(a.z), f2bf(a.w));
    }
    __syncthreads();
    const int dd = tid >> 2;
    const int jj = (tid & 3) * 16;
    u16* dstp = vt + ((size_t)b * D_ + d0 + dd) * S_ + j0 + jj;
    u16 tmp[16];
#pragma unroll
    for (int e = 0; e < 16; ++e) tmp[e] = t[(jj + e) * TP + dd];
    *(s16x8*)dstp = *(s16x8*)tmp;
    *(s16x8*)(dstp + 8) = *(s16x8*)(tmp + 8);
}

// ============ Fused QK^T + masked softmax: S stripe lives in acc regs ============
// Block = (b, qc): rows [qc*32, qc*32+32), all 1024 cols. 8 waves x 128-col stripes.
__global__ __launch_bounds__(512, 2) void fused_qksm(const float* __restrict__ q,
                                                     const u16* __restrict__ Kb,
                                                     const int* __restrict__ rep,
                                                     float* __restrict__ attn) {
    const int bid = blockIdx.x;
    const int xcd = bid & 7, w = bid >> 3;          // 8 XCDs x 64
    const int b = xcd * 2 + (w & 1);                // 2 batches per XCD (L2 locality)
    const int qc = 31 - (w >> 1);                   // LPT: big chunks first
    const int i0 = qc * 32;
    const int ncolt = (qc >> 2) + 1;                // # of 128-col K tiles needed
    const int ncol = ncolt * 128;

    __shared__ u16 lQ[32 * 512];     // 32 KB, unit-swizzled: unit ^= (i&7)
    __shared__ u16 lK[1024 * 32];    // 64 KB, pair-swizzled (128B pairs)
    __shared__ int lrep[1024];
    __shared__ float lred[8][32][2];
    __shared__ float lrs[32][2];

    const int tid = threadIdx.x, lane = tid & 63, wid = tid >> 6;
    const int r15 = lane & 15, g4 = lane >> 4;

    // stage rep mask row for this batch
    {
        int2 rv = ((const int2*)(rep + (size_t)b * S_))[tid];
        lrep[tid * 2] = rv.x;
        lrep[tid * 2 + 1] = rv.y;
    }
    // stage Q (fp32 -> bf16 swizzled LDS), read-once
    {
        const float* qg = q + ((size_t)b * S_ + i0) * D_;
#pragma unroll
        for (int e = 0; e < 4; ++e) {
            int G = e * 512 + tid;               // 0..2047 granules of 8
            int i = G >> 6, c8 = G & 63;
            const float* src = qg + i * D_ + c8 * 8;
            float4 x0 = *(const float4*)src;
            float4 x1 = *(const float4*)(src + 4);
            union { ushort4 h[2]; s16x8 v; } rr;
            rr.h[0] = make_ushort4(f2bf(x0.x), f2bf(x0.y), f2bf(x0.z), f2bf(x0.w));
            rr.h[1] = make_ushort4(f2bf(x1.x), f2bf(x1.y), f2bf(x1.z), f2bf(x1.w));
            int unit = c8 ^ (i & 7);
            *(s16x8*)(lQ + i * 512 + unit * 8) = rr.v;
        }
    }
    __syncthreads();

    const u16* kbase = Kb + (size_t)b * S_ * D_;
    f32x4 acc[2][8] = {};   // [rowfrag][colfrag], cols wid*128 + cf*16 + r15

    for (int kk = 0; kk < 512; kk += 32) {
        // stage K chunk rows [0,ncol) x k [kk,kk+32): GLD16 with pair-swizzled source
        for (int t = 0; t < ncolt; ++t) {
            int ud = t * 512 + tid;              // 16B unit id
            int p = ud >> 3, u = ud & 7;
            int lu = u ^ (p & 7);
            int j = p * 2 + (lu >> 2);
            int k16 = lu & 3;
            GLD16(kbase + (size_t)j * D_ + kk + k16 * 8, lK + t * 4096 + wid * 512);
        }
        __syncthreads();
        if (wid < ncolt) {
            s16x8 av[2], bv[8];
            int c8 = (kk >> 3) + g4;
#pragma unroll
            for (int rf = 0; rf < 2; ++rf) {
                int i = rf * 16 + r15;
                av[rf] = *(const s16x8*)(lQ + i * 512 + (c8 ^ (i & 7)) * 8);
            }
#pragma unroll
            for (int cf = 0; cf < 8; ++cf) {
                int j = wid * 128 + cf * 16 + r15;
                int p = j >> 1;
                int lu = (j & 1) * 4 + g4;
                bv[cf] = *(const s16x8*)(lK + p * 64 + (lu ^ (p & 7)) * 8);
            }
#pragma unroll
            for (int rf = 0; rf < 2; ++rf)
#pragma unroll
                for (int cf = 0; cf < 8; ++cf)
                    acc[rf][cf] = __builtin_amdgcn_mfma_f32_16x16x32_bf16(av[rf], bv[cf], acc[rf][cf], 0, 0, 0);
        }
        __syncthreads();
    }

    // ---------- in-register masked softmax ----------
    const float scale = 0.04419417382415922f;  // 1/sqrt(512)
    int mj[8];
#pragma unroll
    for (int cf = 0; cf < 8; ++cf) mj[cf] = lrep[wid * 128 + cf * 16 + r15];
    int mi_[2][4];
#pragma unroll
    for (int rf = 0; rf < 2; ++rf)
#pragma unroll
        for (int r = 0; r < 4; ++r) mi_[rf][r] = lrep[i0 + rf * 16 + g4 * 4 + r];

    float pm[2][4], ps[2][4];
#pragma unroll
    for (int rf = 0; rf < 2; ++rf)
#pragma unroll
        for (int r = 0; r < 4; ++r) {
            const int i = i0 + rf * 16 + g4 * 4 + r;
            const int im = mi_[rf][r];
            float m = 0.0f;   // masked entries contribute 0 to the max (reference)
#pragma unroll
            for (int cf = 0; cf < 8; ++cf) {
                int j = wid * 128 + cf * 16 + r15;
                if (im && (j < i) && mj[cf])
                    m = fmaxf(m, acc[rf][cf][r] * scale - (float)(i - j));
            }
            float s = 0.0f;
#pragma unroll
            for (int cf = 0; cf < 8; ++cf) {
                int j = wid * 128 + cf * 16 + r15;
                if (im && (j < i) && mj[cf])
                    s += __expf(acc[rf][cf][r] * scale - (float)(i - j) - m);
            }
            // merge (m,s) across the 16 lanes sharing this row
#pragma unroll
            for (int off = 1; off < 16; off <<= 1) {
                float om = __shfl_xor(m, off);
                float os = __shfl_xor(s, off);
                float M = fmaxf(m, om);
                s = s * __expf(m - M) + os * __expf(om - M);
                m = M;
            }
            pm[rf][r] = m;
            ps[rf][r] = s;
        }
    if (r15 == 0) {
#pragma unroll
        for (int rf = 0; rf < 2; ++rf)
#pragma unroll
            for (int r = 0; r < 4; ++r) {
                int rowl = rf * 16 + g4 * 4 + r;
                lred[wid][rowl][0] = pm[rf][r];
                lred[wid][rowl][1] = ps[rf][r];
            }
    }
    __syncthreads();
    if (tid < 32) {
        float M = 0.0f, S = 0.0f;
#pragma unroll
        for (int w2 = 0; w2 < 8; ++w2) M = fmaxf(M, lred[w2][tid][0]);
#pragma unroll
        for (int w2 = 0; w2 < 8; ++w2) S += lred[w2][tid][1] * __expf(lred[w2][tid][0] - M);
        float denom = (S == 0.0f ? 1.0f : S) + 1e-20f;
        lrs[tid][0] = M;
        lrs[tid][1] = 1.0f / denom;
    }
    __syncthreads();

    // ---------- write final P (every position exactly once) ----------
    float* arow = attn + ((size_t)b * S_ + i0) * S_;
#pragma unroll
    for (int rf = 0; rf < 2; ++rf)
#pragma unroll
        for (int r = 0; r < 4; ++r) {
            const int il = rf * 16 + g4 * 4 + r;
            const int i = i0 + il;
            const int im = mi_[rf][r];
            const float M = lrs[il][0], inv = lrs[il][1];
#pragma unroll
            for (int cf = 0; cf < 8; ++cf) {
                int j = wid * 128 + cf * 16 + r15;
                float pv = 0.0f;
                if (im && (j < i) && mj[cf])
                    pv = __expf(acc[rf][cf][r] * scale - (float)(i - j) - M) * inv;
                arow[(size_t)il * S_ + j] = pv;
            }
        }
}

// ============ PV: out = P V, P read fp32 (reg-staged cvt), Vt via GLD16 ============
__device__ __forceinline__ s16x8 frag_swz(const u16* lds, int row, int colbyte) {
    int off = row * 128 + (colbyte ^ ((row & 7) << 4));
    return *(const s16x8*)((const char*)lds + off);
}

__global__ __launch_bounds__(256) void pv3_kernel(const float* __restrict__ attn,
                                                  const u16* __restrict__ Vt,
                                                  float* __restrict__ out) {
    const int bid = blockIdx.x;
    const int xcd = bid & 7, w = bid >> 3;   // 0..63
    const int b = xcd * 2 + (w & 1);
    const int r_ = w >> 1;                   // 0..31
    const int dt = r_ & 3, qt = 7 - (r_ >> 2);   // qt desc (LPT), 4 dt share P panel

    __shared__ u16 lA[128 * 64];
    __shared__ u16 lB[128 * 64];
    const int tid = threadIdx.x, lane = tid & 63, wid = tid >> 6;
    const int l8 = lane >> 3, l7 = lane & 7;
    const int cswz = (l7 ^ l8) * 8;

    const float* ag = attn + ((size_t)b * S_ + (size_t)qt * 128) * S_;
    const u16* bg = Vt + ((size_t)b * D_ + (size_t)dt * 128) * S_;
    const u16* gb[4];
#pragma unroll
    for (int q2 = 0; q2 < 4; ++q2) {
        int seg = wid * 4 + q2;
        gb[q2] = bg + (size_t)(seg * 8 + l8) * S_ + cswz;
    }
    const int au = tid & 7;          // 16B-unit within 64-col row
    const int ar0 = (tid >> 3) * 4;  // 4 rows per thread

    f32x4 acc[4][4] = {};
    const int nk = (qt + 1) * 128;
    const int wr = (wid >> 1) * 64, wc = (wid & 1) * 64;
    const int r15 = lane & 15, cb = (lane >> 4) * 16;

    for (int kk = 0; kk < nk; kk += 64) {
#pragma unroll
        for (int q2 = 0; q2 < 4; ++q2)
            GLD16(gb[q2] + kk, lB + (wid * 4 + q2) * 512);
#pragma unroll
        for (int rr = 0; rr < 4; ++rr) {
            int row = ar0 + rr;
            const float* src = ag + (size_t)row * S_ + kk + au * 8;
            float4 x0 = *(const float4*)src;
            float4 x1 = *(const float4*)(src + 4);
            union { ushort4 h[2]; s16x8 v; } rv;
            rv.h[0] = make_ushort4(f2bf(x0.x), f2bf(x0.y), f2bf(x0.z), f2bf(x0.w));
            rv.h[1] = make_ushort4(f2bf(x1.x), f2bf(x1.y), f2bf(x1.z), f2bf(x1.w));
            *(s16x8*)(lA + row * 64 + (au ^ (row & 7)) * 8) = rv.v;
        }
        __syncthreads();
        s16x8 af[4], bf4[4];
#pragma unroll
        for (int ks = 0; ks < 2; ++ks) {
#pragma unroll
            for (int m = 0; m < 4; ++m) af[m] = frag_swz(lA, wr + m * 16 + r15, ks * 64 + cb);
#pragma unroll
            for (int n = 0; n < 4; ++n) bf4[n] = frag_swz(lB, wc + n * 16 + r15, ks * 64 + cb);
#pragma unroll
            for (int m = 0; m < 4; ++m)
#pragma unroll
                for (int n = 0; n < 4; ++n)
                    acc[m][n] = __builtin_amdgcn_mfma_f32_16x16x32_bf16(af[m], bf4[n], acc[m][n], 0, 0, 0);
        }
        __syncthreads();
    }

    size_t base = ((size_t)b * S_ + (size_t)qt * 128) * D_ + (size_t)dt * 128;
    const int rr2 = (lane >> 4) * 4;
#pragma unroll
    for (int m = 0; m < 4; ++m)
#pragma unroll
        for (int n = 0; n < 4; ++n)
#pragma unroll
            for (int r = 0; r < 4; ++r)
                out[base + (size_t)(wr + m * 16 + rr2 + r) * D_ + wc + n * 16 + r15] =
                    acc[m][n][r];
}

// ======================= legacy fallback path (no ws) =======================

union Frag { s16x8 v; uint2 u[2]; };

__device__ __forceinline__ s16x8 load_frag(const u16* lds, int row, int kq) {
    Frag f;
    const u16* p = lds + row * PITCH + kq;
    f.u[0] = *(const uint2*)p;
    f.u[1] = *(const uint2*)(p + 4);
    return f.v;
}

__device__ __forceinline__ void stage_granule(u16* lds, const float* src, int ldsrc, int g) {
    int row = g >> 2;
    int c8 = (g & 3) * 8;
    const float4* s = (const float4*)(src + (size_t)row * ldsrc + c8);
    float4 x0 = s[0], x1 = s[1];
    *(ushort4*)(lds + row * PITCH + c8) =
        make_ushort4(f2bf(x0.x), f2bf(x0.y), f2bf(x0.z), f2bf(x0.w));
    *(ushort4*)(lds + row * PITCH + c8 + 4) =
        make_ushort4(f2bf(x1.x), f2bf(x1.y), f2bf(x1.z), f2bf(x1.w));
}

__global__ __launch_bounds__(256) void qk_kernel(const float* __restrict__ q,
                                                 const float* __restrict__ k,
                                                 float* __restrict__ attn) {
    const int kt = blockIdx.x, qt = blockIdx.y, b = blockIdx.z;
    if (kt > qt) return;
    __shared__ u16 lA[TILE * PITCH];
    __shared__ u16 lB[TILE * PITCH];
    const int tid = threadIdx.x;
    const int lane = tid & 63;
    const int wid = tid >> 6;
    const int wr = (wid >> 1) * 64, wc = (wid & 1) * 64;
    const int r15 = lane & 15, kq = (lane >> 4) * 8;
    const float* qb = q + ((size_t)b * S_ + (size_t)qt * TILE) * D_;
    const float* kb = k + ((size_t)b * S_ + (size_t)kt * TILE) * D_;
    f32x4 acc[4][4] = {};
    for (int kk = 0; kk < D_; kk += BK) {
        __syncthreads();
        stage_granule(lA, qb + kk, D_, tid);
        stage_granule(lA, qb + kk, D_, tid + 256);
        stage_granule(lB, kb + kk, D_, tid);
        stage_granule(lB, kb + kk, D_, tid + 256);
        __syncthreads();
        s16x8 af[4], bf[4];
#pragma unroll
        for (int m = 0; m < 4; ++m) af[m] = load_frag(lA, wr + m * 16 + r15, kq);
#pragma unroll
        for (int n = 0; n < 4; ++n) bf[n] = load_frag(lB, wc + n * 16 + r15, kq);
#pragma unroll
        for (int m = 0; m < 4; ++m)
#pragma unroll
            for (int n = 0; n < 4; ++n)
                acc[m][n] = __builtin_amdgcn_mfma_f32_16x16x32_bf16(af[m], bf[n], acc[m][n], 0, 0, 0);
    }
    const float scale = 0.04419417382415922f;
    size_t base = ((size_t)b * S_ + (size_t)qt * TILE) * S_ + (size_t)kt * TILE;
    const int rr = (lane >> 4) * 4;
#pragma unroll
    for (int m = 0; m < 4; ++m)
#pragma unroll
        for (int n = 0; n < 4; ++n)
#pragma unroll
            for (int r = 0; r < 4; ++r)
                attn[base + (size_t)(wr + m * 16 + rr + r) * S_ + wc + n * 16 + r15] =
                    acc[m][n][r] * scale;
}

__global__ __launch_bounds__(256) void sm_kernel(const int* __restrict__ rep_mask,
                                                 float* __restrict__ attn) {
    const int i = blockIdx.x, b = blockIdx.y;
    const int tid = threadIdx.x;
    const int lane = tid & 63, wid = tid >> 6;
    float* row = attn + ((size_t)b * S_ + i) * S_;
    const int* rm = rep_mask + (size_t)b * S_;
    __shared__ float red[8];
    const int mi = rm[i];
    const int j0 = tid * 4;
    int4 m4 = ((const int4*)rm)[tid];
    float4 lv = make_float4(0.f, 0.f, 0.f, 0.f);
    if (mi != 0 && j0 < i) lv = *(const float4*)(row + j0);
    const int mv[4] = {m4.x, m4.y, m4.z, m4.w};
    const float lf[4] = {lv.x, lv.y, lv.z, lv.w};
    float vec[4];
    bool val[4];
    float mymax = 0.0f;
#pragma unroll
    for (int e = 0; e < 4; ++e) {
        int j = j0 + e;
        val[e] = (mi != 0) && (j < i) && (mv[e] != 0);
        vec[e] = lf[e] - (float)(i - j);
        if (val[e]) mymax = fmaxf(mymax, vec[e]);
    }
#pragma unroll
    for (int off = 32; off > 0; off >>= 1) mymax = fmaxf(mymax, __shfl_down(mymax, off));
    if (lane == 0) red[wid] = mymax;
    __syncthreads();
    const float m = fmaxf(fmaxf(red[0], red[1]), fmaxf(red[2], red[3]));
    float ex[4];
    float mysum = 0.0f;
#pragma unroll
    for (int e = 0; e < 4; ++e) {
        ex[e] = val[e] ? expf(vec[e] - m) : 0.0f;
        mysum += ex[e];
    }
#pragma unroll
    for (int off = 32; off > 0; off >>= 1) mysum += __shfl_down(mysum, off);
    if (lane == 0) red[4 + wid] = mysum;
    __syncthreads();
    const float ssum = red[4] + red[5] + red[6] + red[7];
    const float denom = ssum + (ssum == 0.0f ? 1.0f : 0.0f) + 1e-20f;
    const float inv = 1.0f / denom;
    *(float4*)(row + j0) = make_float4(ex[0] * inv, ex[1] * inv, ex[2] * inv, ex[3] * inv);
}

__global__ __launch_bounds__(256) void pv_kernel(const float* __restrict__ attn,
                                                 const float* __restrict__ v,
                                                 float* __restrict__ out) {
    const int dt = blockIdx.x, qt = blockIdx.y, b = blockIdx.z;
    __shared__ u16 lP[TILE * PITCH];
    __shared__ u16 lV[TILE * PITCH];
    const int tid = threadIdx.x;
    const int lane = tid & 63;
    const int wid = tid >> 6;
    const int wr = (wid >> 1) * 64, wc = (wid & 1) * 64;
    const int r15 = lane & 15, kq = (lane >> 4) * 8;
    const float* pb = attn + ((size_t)b * S_ + (size_t)qt * TILE) * S_;
    const float* vb = v + (size_t)b * S_ * D_ + (size_t)dt * TILE;
    const int vd0 = (tid & 31) * 4;
    const int vj0 = (tid >> 5) * 4;
    f32x4 acc[4][4] = {};
    const int nk = (qt + 1) * TILE;
    for (int kk = 0; kk < nk; kk += BK) {
        __syncthreads();
        stage_granule(lP, pb + kk, S_, tid);
        stage_granule(lP, pb + kk, S_, tid + 256);
        {
            const float* vs = vb + (size_t)(kk + vj0) * D_ + vd0;
            float4 r0 = *(const float4*)vs;
            float4 r1 = *(const float4*)(vs + D_);
            float4 r2 = *(const float4*)(vs + 2 * D_);
            float4 r3 = *(const float4*)(vs + 3 * D_);
            *(ushort4*)(lV + (vd0 + 0) * PITCH + vj0) = make_ushort4(f2bf(r0.x), f2bf(r1.x), f2bf(r2.x), f2bf(r3.x));
            *(ushort4*)(lV + (vd0 + 1) * PITCH + vj0) = make_ushort4(f2bf(r0.y), f2bf(r1.y), f2bf(r2.y), f2bf(r3.y));
            *(ushort4*)(lV + (vd0 + 2) * PITCH + vj0) = make_ushort4(f2bf(r0.z), f2bf(r1.z), f2bf(r2.z), f2bf(r3.z));
            *(ushort4*)(lV + (vd0 + 3) * PITCH + vj0) = make_ushort4(f2bf(r0.w), f2bf(r1.w), f2bf(r2.w), f2bf(r3.w));
        }
        __syncthreads();
        s16x8 af[4], bf[4];
#pragma unroll
        for (int m = 0; m < 4; ++m) af[m] = load_frag(lP, wr + m * 16 + r15, kq);
#pragma unroll
        for (int n = 0; n < 4; ++n) bf[n] = load_frag(lV, wc + n * 16 + r15, kq);
#pragma unroll
        for (int m = 0; m < 4; ++m)
#pragma unroll
            for (int n = 0; n < 4; ++n)
                acc[m][n] = __builtin_amdgcn_mfma_f32_16x16x32_bf16(af[m], bf[n], acc[m][n], 0, 0, 0);
    }
    size_t base = ((size_t)b * S_ + (size_t)qt * TILE) * D_ + (size_t)dt * TILE;
    const int rr = (lane >> 4) * 4;
#pragma unroll
    for (int m = 0; m < 4; ++m)
#pragma unroll
        for (int n = 0; n < 4; ++n)
#pragma unroll
            for (int r = 0; r < 4; ++r)
                out[base + (size_t)(wr + m * 16 + rr + r) * D_ + wc + n * 16 + r15] =
                    acc[m][n][r];
}

extern "C" void kernel_launch(void* const* d_in, const int* in_sizes, int n_in,
                              void* d_out, int out_size, void* d_ws, size_t ws_size,
                              hipStream_t stream) {
    const float* q = (const float*)d_in[0];
    const float* k = (const float*)d_in[1];
    const float* v = (const float*)d_in[2];
    const int* rep = (const int*)d_in[3];
    float* out = (float*)d_out;
    float* attn = out + (size_t)B_ * S_ * D_;   // second output region [B,S,S]

    const size_t nqk = (size_t)B_ * S_ * D_;    // 8.4M elems
    const size_t need = 2 * nqk * sizeof(u16);  // Kb + Vt = 33.6 MB
    if (ws_size >= need) {
        u16* Kb = (u16*)d_ws;
        u16* Vt = Kb + nqk;
        cvt_kernel<<<nqk / (8 * 256), 256, 0, stream>>>(k, Kb);
        trv_kernel<<<dim3(D_ / 64, S_ / 64, B_), 256, 0, stream>>>(v, Vt);
        fused_qksm<<<512, 512, 0, stream>>>(q, Kb, rep, attn);
        pv3_kernel<<<512, 256, 0, stream>>>(attn, Vt, out);
    } else {
        qk_kernel<<<dim3(S_ / TILE, S_ / TILE, B_), 256, 0, stream>>>(q, k, attn);
        sm_kernel<<<dim3(S_, B_), 256, 0, stream>>>(rep, attn);
        pv_kernel<<<dim3(D_ / TILE, S_ / TILE, B_), 256, 0, stream>>>(attn, v, out);
    }
}